// Round 2
// baseline (272.529 us; speedup 1.0000x reference)
//
#include <hip/hip_runtime.h>
#include <hip/hip_bf16.h>
#include <cstdint>

#define B_ 2
#define S_ 4096
#define E_ 768
#define H_ 12
#define D_ 64

typedef __bf16 bf16x8 __attribute__((ext_vector_type(8)));
typedef short short4_t __attribute__((ext_vector_type(4)));
typedef float f32x4 __attribute__((ext_vector_type(4)));
typedef unsigned short ushort8 __attribute__((ext_vector_type(8)));
typedef unsigned short ushort4v __attribute__((ext_vector_type(4)));

static __device__ __forceinline__ unsigned short f2bf(float f) {
    union { float f; uint32_t u; } v; v.f = f;
    uint32_t u = v.u;
    u += 0x7FFFu + ((u >> 16) & 1u);
    return (unsigned short)(u >> 16);
}

static __device__ __forceinline__ f32x4 mfma16(short4_t a, short4_t b, f32x4 c) {
#if __has_builtin(__builtin_amdgcn_mfma_f32_16x16x16bf16_1k)
    return __builtin_amdgcn_mfma_f32_16x16x16bf16_1k(a, b, c, 0, 0, 0);
#else
    asm volatile("v_mfma_f32_16x16x16_bf16 %0, %1, %2, %0" : "+v"(c) : "v"(a), "v"(b));
    return c;
#endif
}

// ---------------- convert hidden_states fp32 -> bf16 ----------------
__global__ void cvt_x(const float* __restrict__ x, unsigned short* __restrict__ xb, int n4) {
    int i = blockIdx.x * blockDim.x + threadIdx.x;
    int stride = gridDim.x * blockDim.x;
    for (; i < n4; i += stride) {
        float4 f = ((const float4*)x)[i];
        ushort4v o;
        o.x = f2bf(f.x); o.y = f2bf(f.y); o.z = f2bf(f.z); o.w = f2bf(f.w);
        ((ushort4v*)xb)[i] = o;
    }
}

// ---------------- convert + transpose weights: WT[n][k] = W[k][n], bf16 ----------------
__global__ void cvt_w(const float* __restrict__ Wq, const float* __restrict__ Wk,
                      const float* __restrict__ Wv, unsigned short* __restrict__ wt) {
    __shared__ float tl[32][33];
    int wsel = blockIdx.z;
    const float* src = wsel == 0 ? Wq : (wsel == 1 ? Wk : Wv);
    int tx = threadIdx.x, ty = threadIdx.y;
    int n0 = blockIdx.x * 32, k0 = blockIdx.y * 32;
    for (int i = 0; i < 4; i++) {
        int k = k0 + ty + i * 8;
        tl[ty + i * 8][tx] = src[(size_t)k * E_ + n0 + tx];
    }
    __syncthreads();
    unsigned short* dst = wt + (size_t)wsel * E_ * E_;
    for (int i = 0; i < 4; i++) {
        int n = n0 + ty + i * 8;
        dst[(size_t)n * E_ + k0 + tx] = f2bf(tl[tx][ty + i * 8]);
    }
}

// ---------------- QKV GEMM: Q,K row-major bf16; V stored TRANSPOSED [b][h][d][s] ----------------
#define GM 128
#define GN 64
#define AST 56

__global__ __launch_bounds__(256) void qkv_gemm(const unsigned short* __restrict__ xb,
        const unsigned short* __restrict__ wt,
        const float* __restrict__ biasq, const float* __restrict__ biask,
        const float* __restrict__ biasv,
        unsigned short* __restrict__ qk, unsigned short* __restrict__ vtg) {
    __shared__ unsigned short alds[GM * AST];
    int m0 = blockIdx.x * GM;
    int nblk = blockIdx.y * GN;          // 0..2304
    int wsel = nblk / E_;
    int nn0 = nblk % E_;
    const float* bias = wsel == 0 ? biasq : (wsel == 1 ? biask : biasv);
    float scale = wsel == 0 ? 0.125f : 1.0f;
    int t = threadIdx.x;
    int lane = t & 63, wv = t >> 6;
    int wm = wv >> 1, wn = wv & 1;
    int l15 = lane & 15, l4 = lane >> 4;

    f32x4 acc[4][2];
    for (int f = 0; f < 4; f++)
        for (int nf = 0; nf < 2; nf++)
            acc[f][nf] = (f32x4){0.f, 0.f, 0.f, 0.f};

    int srow = t >> 1;
    int scol = (t & 1) * 16;
    const unsigned short* xrow = xb + (size_t)(m0 + srow) * E_ + scol;
    unsigned short* sdst = alds + srow * AST + scol;
    const unsigned short* wbase = wt + (size_t)wsel * E_ * E_;

    for (int kk = 0; kk < E_; kk += 32) {
        ushort8 a0 = *(const ushort8*)(xrow + kk);
        ushort8 a1 = *(const ushort8*)(xrow + kk + 8);
        *(ushort8*)(sdst) = a0;
        *(ushort8*)(sdst + 8) = a1;
        __syncthreads();
        bf16x8 bfr[2];
        for (int nf = 0; nf < 2; nf++) {
            int nn = nn0 + wn * 32 + nf * 16 + l15;
            bfr[nf] = *(const bf16x8*)(wbase + (size_t)nn * E_ + kk + l4 * 8);
        }
        for (int f = 0; f < 4; f++) {
            bf16x8 afr = *(const bf16x8*)(alds + (wm * 64 + f * 16 + l15) * AST + l4 * 8);
            acc[f][0] = __builtin_amdgcn_mfma_f32_16x16x32_bf16(afr, bfr[0], acc[f][0], 0, 0, 0);
            acc[f][1] = __builtin_amdgcn_mfma_f32_16x16x32_bf16(afr, bfr[1], acc[f][1], 0, 0, 0);
        }
        __syncthreads();
    }
    for (int f = 0; f < 4; f++) {
        int row0 = m0 + wm * 64 + f * 16;
        for (int nf = 0; nf < 2; nf++) {
            int nn = nn0 + wn * 32 + nf * 16 + l15;
            float bb = bias[nn];
            for (int r = 0; r < 4; r++) {
                int row = row0 + l4 * 4 + r;
                float v = (acc[f][nf][r] + bb) * scale;
                unsigned short bv = f2bf(v);
                if (wsel < 2) {
                    qk[(size_t)wsel * 8192 * E_ + (size_t)row * E_ + nn] = bv;
                } else {
                    int b = row >> 12, s = row & 4095;
                    int hh = nn >> 6, dd = nn & 63;
                    vtg[((size_t)(b * H_ + hh) * D_ + dd) * S_ + s] = bv;
                }
            }
        }
    }
}

// ---------------- banded flash attention, swapped-QK^T, zero LDS ----------------
__global__ __launch_bounds__(256) void attn(const unsigned short* __restrict__ qk,
        const unsigned short* __restrict__ vtg,
        const float* __restrict__ amask, float* __restrict__ out) {
    int qt = blockIdx.x, h = blockIdx.y, b = blockIdx.z;
    int t = threadIdx.x, lane = t & 63, wv = t >> 6;
    int l15 = lane & 15, l4 = lane >> 4;
    const unsigned short* qp = qk;
    const unsigned short* kp = qk + (size_t)8192 * E_;
    size_t rowbase = (size_t)b * S_;
    int hcol = h * D_;
    const unsigned short* vth = vtg + (size_t)(b * H_ + h) * D_ * S_;
    const float* amb = amask + (size_t)b * S_;

    int q0 = qt * 64 + wv * 16;
    int myq = q0 + l15;
    bf16x8 qf[2];
    {
        const unsigned short* qrow = qp + (rowbase + myq) * E_ + hcol;
        qf[0] = *(const bf16x8*)(qrow + l4 * 8);
        qf[1] = *(const bf16x8*)(qrow + 32 + l4 * 8);
    }
    // hoisted V^T row bases (d = dblk*16 + l15)
    const unsigned short* vrow[4];
    for (int dblk = 0; dblk < 4; dblk++)
        vrow[dblk] = vth + (size_t)(dblk * 16 + l15) * S_;

    float mrun = -1e30f, lrun = 0.f;
    f32x4 oacc[4];
    for (int dblk = 0; dblk < 4; dblk++) oacc[dblk] = (f32x4){0.f, 0.f, 0.f, 0.f};

    int kt0 = (q0 - 256) & ~31;

    for (int it = 0; it < 17; ++it) {
        int kg = kt0 + it * 32;
        // --- K A-frags + swapped QK^T : st[nt] holds S^T[key=kg+nt*16+l4*4+r][q=myq]
        f32x4 st[2];
        for (int nt = 0; nt < 2; ++nt) {
            int key = kg + nt * 16 + l15;
            int keyc = min(max(key, 0), S_ - 1);
            const unsigned short* krow = kp + (rowbase + keyc) * E_ + hcol;
            bf16x8 kf0 = *(const bf16x8*)(krow + l4 * 8);
            bf16x8 kf1 = *(const bf16x8*)(krow + 32 + l4 * 8);
            f32x4 z = (f32x4){0.f, 0.f, 0.f, 0.f};
            z = __builtin_amdgcn_mfma_f32_16x16x32_bf16(kf0, qf[0], z, 0, 0, 0);
            st[nt] = __builtin_amdgcn_mfma_f32_16x16x32_bf16(kf1, qf[1], z, 0, 0, 0);
        }
        // --- V^T B-frags from global: vb[nt][dblk][j] = V[kg+nt*16+l4*4+j][dblk*16+l15]
        short4_t vb[2][4];
        for (int nt = 0; nt < 2; nt++) {
            int kk = kg + nt * 16 + l4 * 4;
            int kkc = min(max(kk, 0), S_ - 4);
            for (int dblk = 0; dblk < 4; dblk++)
                vb[nt][dblk] = *(const short4_t*)(vrow[dblk] + kkc);
        }
        // --- additive attention mask per key (float4 over r)
        float fm[2][4];
        for (int nt = 0; nt < 2; nt++) {
            int idx = kg + nt * 16 + l4 * 4;
            if (idx >= 0 && idx < S_) {
                float4 a4 = *(const float4*)(amb + idx);
                fm[nt][0] = (a4.x != 0.f) ? -10000.f : 0.f;
                fm[nt][1] = (a4.y != 0.f) ? -10000.f : 0.f;
                fm[nt][2] = (a4.z != 0.f) ? -10000.f : 0.f;
                fm[nt][3] = (a4.w != 0.f) ? -10000.f : 0.f;
            } else {
                fm[nt][0] = fm[nt][1] = fm[nt][2] = fm[nt][3] = 0.f;
            }
        }
        // --- validity + online softmax (per-lane query = myq)
        float p[2][4];
        bool vld[2][4];
        float mtile = -1e30f;
        for (int nt = 0; nt < 2; nt++)
            for (int r = 0; r < 4; r++) {
                int key = kg + nt * 16 + l4 * 4 + r;
                int dd = key - myq;
                bool valid = (key >= 0) && (key < S_) && (dd <= 256) && (dd >= -256);
                vld[nt][r] = valid;
                float sv = valid ? (st[nt][r] + fm[nt][r]) : -1e30f;
                p[nt][r] = sv;
                mtile = fmaxf(mtile, sv);
            }
        mtile = fmaxf(mtile, __shfl_xor(mtile, 16));
        mtile = fmaxf(mtile, __shfl_xor(mtile, 32));
        float mnew = fmaxf(mrun, mtile);
        float sc = __expf(mrun - mnew);
        mrun = mnew;
        float psum = 0.f;
        for (int nt = 0; nt < 2; nt++)
            for (int r = 0; r < 4; r++) {
                float e = vld[nt][r] ? __expf(p[nt][r] - mnew) : 0.f;
                p[nt][r] = e;
                psum += e;
            }
        psum += __shfl_xor(psum, 16);
        psum += __shfl_xor(psum, 32);
        lrun = lrun * sc + psum;
        // --- P -> bf16 A-frags (stays in registers)
        short4_t pa[2];
        for (int nt = 0; nt < 2; nt++)
            for (int r = 0; r < 4; r++)
                pa[nt][r] = (short)f2bf(p[nt][r]);
        // --- rescale O by sc (sc lives at lane = query index 0..15)
        for (int r = 0; r < 4; r++) {
            float s = __shfl(sc, l4 * 4 + r);
            oacc[0][r] *= s; oacc[1][r] *= s; oacc[2][r] *= s; oacc[3][r] *= s;
        }
        // --- PV: O[q=l4*4+r][d=dblk*16+l15]
        for (int dblk = 0; dblk < 4; dblk++) {
            oacc[dblk] = mfma16(pa[0], vb[0][dblk], oacc[dblk]);
            oacc[dblk] = mfma16(pa[1], vb[1][dblk], oacc[dblk]);
        }
    }
    // --- epilogue
    for (int r = 0; r < 4; r++) {
        int row = q0 + l4 * 4 + r;
        float lv = __shfl(lrun, l4 * 4 + r);
        float inv = 1.0f / lv;
        if (amb[row] < 0.f) inv = 0.f;
        for (int dblk = 0; dblk < 4; dblk++)
            out[(rowbase + row) * E_ + hcol + dblk * 16 + l15] = oacc[dblk][r] * inv;
    }
}

extern "C" void kernel_launch(void* const* d_in, const int* in_sizes, int n_in,
                              void* d_out, int out_size, void* d_ws, size_t ws_size,
                              hipStream_t stream) {
    const float* hs = (const float*)d_in[0];
    const float* am = (const float*)d_in[1];
    const float* Wq = (const float*)d_in[2];
    const float* bq = (const float*)d_in[3];
    const float* Wk = (const float*)d_in[4];
    const float* bk = (const float*)d_in[5];
    const float* Wv = (const float*)d_in[6];
    const float* bv = (const float*)d_in[7];
    float* out = (float*)d_out;
    unsigned short* xb  = (unsigned short*)d_ws;                  // 8192*768
    unsigned short* wtp = xb + (size_t)8192 * E_;                 // 3*768*768
    unsigned short* qkb = wtp + (size_t)3 * E_ * E_;              // 2*8192*768 (Q,K)
    unsigned short* vtg = qkb + (size_t)2 * 8192 * E_;            // 2*12*64*4096 (V^T)

    hipLaunchKernelGGL(cvt_x, dim3(2048), dim3(256), 0, stream, hs, xb, 8192 * E_ / 4);
    hipLaunchKernelGGL(cvt_w, dim3(24, 24, 3), dim3(32, 8), 0, stream, Wq, Wk, Wv, wtp);
    hipLaunchKernelGGL(qkv_gemm, dim3(64, 36), dim3(256), 0, stream, xb, wtp, bq, bk, bv, qkb, vtg);
    hipLaunchKernelGGL(attn, dim3(64, 12, 2), dim3(256), 0, stream, qkb, vtg, am, out);
}

// Round 3
// 258.454 us; speedup vs baseline: 1.0545x; 1.0545x over previous
//
#include <hip/hip_runtime.h>
#include <hip/hip_bf16.h>
#include <cstdint>

#define B_ 2
#define S_ 4096
#define E_ 768
#define H_ 12
#define D_ 64

typedef __bf16 bf16x8 __attribute__((ext_vector_type(8)));
typedef short short4_t __attribute__((ext_vector_type(4)));
typedef float f32x4 __attribute__((ext_vector_type(4)));
typedef unsigned short ushort8 __attribute__((ext_vector_type(8)));
typedef unsigned short ushort4v __attribute__((ext_vector_type(4)));

static __device__ __forceinline__ unsigned short f2bf(float f) {
    union { float f; uint32_t u; } v; v.f = f;
    uint32_t u = v.u;
    u += 0x7FFFu + ((u >> 16) & 1u);
    return (unsigned short)(u >> 16);
}

static __device__ __forceinline__ f32x4 mfma16(short4_t a, short4_t b, f32x4 c) {
#if __has_builtin(__builtin_amdgcn_mfma_f32_16x16x16bf16_1k)
    return __builtin_amdgcn_mfma_f32_16x16x16bf16_1k(a, b, c, 0, 0, 0);
#else
    asm volatile("v_mfma_f32_16x16x16_bf16 %0, %1, %2, %0" : "+v"(c) : "v"(a), "v"(b));
    return c;
#endif
}

// ---------------- convert hidden_states fp32 -> bf16 ----------------
__global__ void cvt_x(const float* __restrict__ x, unsigned short* __restrict__ xb, int n4) {
    int i = blockIdx.x * blockDim.x + threadIdx.x;
    int stride = gridDim.x * blockDim.x;
    for (; i < n4; i += stride) {
        float4 f = ((const float4*)x)[i];
        ushort4v o;
        o.x = f2bf(f.x); o.y = f2bf(f.y); o.z = f2bf(f.z); o.w = f2bf(f.w);
        ((ushort4v*)xb)[i] = o;
    }
}

// ---------------- convert + transpose weights: WT[n][k] = W[k][n], bf16 ----------------
__global__ void cvt_w(const float* __restrict__ Wq, const float* __restrict__ Wk,
                      const float* __restrict__ Wv, unsigned short* __restrict__ wt) {
    __shared__ float tl[32][33];
    int wsel = blockIdx.z;
    const float* src = wsel == 0 ? Wq : (wsel == 1 ? Wk : Wv);
    int tx = threadIdx.x, ty = threadIdx.y;
    int n0 = blockIdx.x * 32, k0 = blockIdx.y * 32;
    for (int i = 0; i < 4; i++) {
        int k = k0 + ty + i * 8;
        tl[ty + i * 8][tx] = src[(size_t)k * E_ + n0 + tx];
    }
    __syncthreads();
    unsigned short* dst = wt + (size_t)wsel * E_ * E_;
    for (int i = 0; i < 4; i++) {
        int n = n0 + ty + i * 8;
        dst[(size_t)n * E_ + k0 + tx] = f2bf(tl[tx][ty + i * 8]);
    }
}

// ---------------- QKV GEMM: Q,K row-major bf16; V stored TRANSPOSED [b][h][d][s] ----------------
#define GM 128
#define GN 64
#define AST 56

__global__ __launch_bounds__(256) void qkv_gemm(const unsigned short* __restrict__ xb,
        const unsigned short* __restrict__ wt,
        const float* __restrict__ biasq, const float* __restrict__ biask,
        const float* __restrict__ biasv,
        unsigned short* __restrict__ qk, unsigned short* __restrict__ vtg) {
    __shared__ unsigned short alds[GM * AST];
    int m0 = blockIdx.x * GM;
    int nblk = blockIdx.y * GN;          // 0..2304
    int wsel = nblk / E_;
    int nn0 = nblk % E_;
    const float* bias = wsel == 0 ? biasq : (wsel == 1 ? biask : biasv);
    float scale = wsel == 0 ? 0.125f : 1.0f;
    int t = threadIdx.x;
    int lane = t & 63, wv = t >> 6;
    int wm = wv >> 1, wn = wv & 1;
    int l15 = lane & 15, l4 = lane >> 4;

    f32x4 acc[4][2];
    for (int f = 0; f < 4; f++)
        for (int nf = 0; nf < 2; nf++)
            acc[f][nf] = (f32x4){0.f, 0.f, 0.f, 0.f};

    int srow = t >> 1;
    int scol = (t & 1) * 16;
    const unsigned short* xrow = xb + (size_t)(m0 + srow) * E_ + scol;
    unsigned short* sdst = alds + srow * AST + scol;
    const unsigned short* wbase = wt + (size_t)wsel * E_ * E_;

    for (int kk = 0; kk < E_; kk += 32) {
        ushort8 a0 = *(const ushort8*)(xrow + kk);
        ushort8 a1 = *(const ushort8*)(xrow + kk + 8);
        *(ushort8*)(sdst) = a0;
        *(ushort8*)(sdst + 8) = a1;
        __syncthreads();
        bf16x8 bfr[2];
        for (int nf = 0; nf < 2; nf++) {
            int nn = nn0 + wn * 32 + nf * 16 + l15;
            bfr[nf] = *(const bf16x8*)(wbase + (size_t)nn * E_ + kk + l4 * 8);
        }
        for (int f = 0; f < 4; f++) {
            bf16x8 afr = *(const bf16x8*)(alds + (wm * 64 + f * 16 + l15) * AST + l4 * 8);
            acc[f][0] = __builtin_amdgcn_mfma_f32_16x16x32_bf16(afr, bfr[0], acc[f][0], 0, 0, 0);
            acc[f][1] = __builtin_amdgcn_mfma_f32_16x16x32_bf16(afr, bfr[1], acc[f][1], 0, 0, 0);
        }
        __syncthreads();
    }
    for (int f = 0; f < 4; f++) {
        int row0 = m0 + wm * 64 + f * 16;
        for (int nf = 0; nf < 2; nf++) {
            int nn = nn0 + wn * 32 + nf * 16 + l15;
            float bb = bias[nn];
            for (int r = 0; r < 4; r++) {
                int row = row0 + l4 * 4 + r;
                float v = (acc[f][nf][r] + bb) * scale;
                unsigned short bv = f2bf(v);
                if (wsel < 2) {
                    qk[(size_t)wsel * 8192 * E_ + (size_t)row * E_ + nn] = bv;
                } else {
                    int b = row >> 12, s = row & 4095;
                    int hh = nn >> 6, dd = nn & 63;
                    vtg[((size_t)(b * H_ + hh) * D_ + dd) * S_ + s] = bv;
                }
            }
        }
    }
}

// ---------------- banded flash attention: swapped QK^T, K double-buffer, XCD swizzle ----------------
struct KBuf {
    bf16x8 k0[2];
    bf16x8 k1[2];
    float badd[2][4];   // per-key additive: 0 / -10000 (mask) / -1e30 (invalid)
};

__global__ __launch_bounds__(256) void attn(const unsigned short* __restrict__ qk,
        const unsigned short* __restrict__ vtg,
        const float* __restrict__ amask, float* __restrict__ out) {
    // XCD-pinning decode: all 64 q-tiles of one (b,h) share one XCD's L2
    int bid = blockIdx.x;
    int xcd = bid & 7;
    int j = bid >> 3;           // 0..191
    int qt = j & 63;
    int p = xcd + 8 * (j >> 6); // 0..23  (b,h) pair
    int h = p % H_;
    int b = p / H_;

    int t = threadIdx.x, lane = t & 63, wv = t >> 6;
    int l15 = lane & 15, l4 = lane >> 4;
    const unsigned short* qp = qk;
    const unsigned short* kp = qk + (size_t)8192 * E_;
    size_t rowbase = (size_t)b * S_;
    int hcol = h * D_;
    const unsigned short* vth = vtg + (size_t)(b * H_ + h) * D_ * S_;
    const float* amb = amask + (size_t)b * S_;

    int q0 = qt * 64 + wv * 16;
    int myq = q0 + l15;
    bf16x8 qf[2];
    {
        const unsigned short* qrow = qp + (rowbase + myq) * E_ + hcol;
        qf[0] = *(const bf16x8*)(qrow + l4 * 8);
        qf[1] = *(const bf16x8*)(qrow + 32 + l4 * 8);
    }
    const unsigned short* vrow[4];
    #pragma unroll
    for (int dblk = 0; dblk < 4; dblk++)
        vrow[dblk] = vth + (size_t)(dblk * 16 + l15) * S_;

    float mrun = -1e8f, lrun = 0.f;
    f32x4 oacc[4];
    #pragma unroll
    for (int dblk = 0; dblk < 4; dblk++) oacc[dblk] = (f32x4){0.f, 0.f, 0.f, 0.f};

    int kt0 = (q0 - 256) & ~31;

    auto load_k = [&](int itl, KBuf& kb) {
        int kg = kt0 + itl * 32;
        #pragma unroll
        for (int nt = 0; nt < 2; nt++) {
            int key = kg + nt * 16 + l15;
            int keyc = min(max(key, 0), S_ - 1);
            const unsigned short* krow = kp + (rowbase + keyc) * E_ + hcol;
            kb.k0[nt] = *(const bf16x8*)(krow + l4 * 8);
            kb.k1[nt] = *(const bf16x8*)(krow + 32 + l4 * 8);
            int idx = kg + nt * 16 + l4 * 4;   // 4-aligned key base for this lane's rows
            float4 a4 = make_float4(0.f, 0.f, 0.f, 0.f);
            if (idx >= 0 && idx <= S_ - 4) a4 = *(const float4*)(amb + idx);
            #pragma unroll
            for (int r = 0; r < 4; r++) {
                int key2 = idx + r;
                int dd = key2 - myq;
                bool valid = (key2 >= 0) && (key2 < S_) && (dd <= 256) && (dd >= -256);
                float av = (r == 0) ? a4.x : (r == 1) ? a4.y : (r == 2) ? a4.z : a4.w;
                kb.badd[nt][r] = valid ? ((av != 0.f) ? -10000.f : 0.f) : -1e30f;
            }
        }
    };

    auto tile = [&](KBuf& cur, int itl, KBuf* nxt) {
        int kg = kt0 + itl * 32;
        // --- issue V loads early (consumed ~end of iter)
        short4_t vb[2][4];
        #pragma unroll
        for (int nt = 0; nt < 2; nt++) {
            int kk = kg + nt * 16 + l4 * 4;
            int kkc = min(max(kk, 0), S_ - 4);
            #pragma unroll
            for (int dblk = 0; dblk < 4; dblk++)
                vb[nt][dblk] = *(const short4_t*)(vrow[dblk] + kkc);
        }
        // --- prefetch next K tile (consumed next iter)
        if (nxt) load_k(itl + 1, *nxt);
        // --- swapped QK^T: st[nt][r] = S[key=kg+nt*16+l4*4+r][q=myq]
        f32x4 st[2];
        #pragma unroll
        for (int nt = 0; nt < 2; nt++) {
            f32x4 z = (f32x4){0.f, 0.f, 0.f, 0.f};
            z = __builtin_amdgcn_mfma_f32_16x16x32_bf16(cur.k0[nt], qf[0], z, 0, 0, 0);
            st[nt] = __builtin_amdgcn_mfma_f32_16x16x32_bf16(cur.k1[nt], qf[1], z, 0, 0, 0);
        }
        // --- softmax (defer-max, THR=8)
        float sv[2][4];
        float mtile = -1e30f;
        #pragma unroll
        for (int nt = 0; nt < 2; nt++)
            #pragma unroll
            for (int r = 0; r < 4; r++) {
                sv[nt][r] = st[nt][r] + cur.badd[nt][r];
                mtile = fmaxf(mtile, sv[nt][r]);
            }
        mtile = fmaxf(mtile, __shfl_xor(mtile, 16));
        mtile = fmaxf(mtile, __shfl_xor(mtile, 32));
        if (__any(mtile - mrun > 8.f)) {
            float mnew = fmaxf(mrun, mtile);
            float sc = __expf(mrun - mnew);
            mrun = mnew;
            lrun *= sc;
            #pragma unroll
            for (int r = 0; r < 4; r++) {
                float s = __shfl(sc, l4 * 4 + r);
                oacc[0][r] *= s; oacc[1][r] *= s; oacc[2][r] *= s; oacc[3][r] *= s;
            }
        }
        float psum = 0.f;
        short4_t pa[2];
        #pragma unroll
        for (int nt = 0; nt < 2; nt++)
            #pragma unroll
            for (int r = 0; r < 4; r++) {
                float e = __expf(sv[nt][r] - mrun);
                psum += e;
                pa[nt][r] = (short)f2bf(e);
            }
        psum += __shfl_xor(psum, 16);
        psum += __shfl_xor(psum, 32);
        lrun += psum;
        // --- PV
        #pragma unroll
        for (int dblk = 0; dblk < 4; dblk++) {
            oacc[dblk] = mfma16(pa[0], vb[0][dblk], oacc[dblk]);
            oacc[dblk] = mfma16(pa[1], vb[1][dblk], oacc[dblk]);
        }
    };

    KBuf ka, kb_;
    load_k(0, ka);
    #pragma unroll 1
    for (int it = 0; it < 16; it += 2) {
        tile(ka, it, &kb_);
        tile(kb_, it + 1, &ka);
    }
    tile(ka, 16, nullptr);

    // --- epilogue
    #pragma unroll
    for (int r = 0; r < 4; r++) {
        int row = q0 + l4 * 4 + r;
        float lv = __shfl(lrun, l4 * 4 + r);
        float inv = 1.0f / lv;
        if (amb[row] < 0.f) inv = 0.f;
        #pragma unroll
        for (int dblk = 0; dblk < 4; dblk++)
            out[(rowbase + row) * E_ + hcol + dblk * 16 + l15] = oacc[dblk][r] * inv;
    }
}

extern "C" void kernel_launch(void* const* d_in, const int* in_sizes, int n_in,
                              void* d_out, int out_size, void* d_ws, size_t ws_size,
                              hipStream_t stream) {
    const float* hs = (const float*)d_in[0];
    const float* am = (const float*)d_in[1];
    const float* Wq = (const float*)d_in[2];
    const float* bq = (const float*)d_in[3];
    const float* Wk = (const float*)d_in[4];
    const float* bk = (const float*)d_in[5];
    const float* Wv = (const float*)d_in[6];
    const float* bv = (const float*)d_in[7];
    float* out = (float*)d_out;
    unsigned short* xb  = (unsigned short*)d_ws;                  // 8192*768
    unsigned short* wtp = xb + (size_t)8192 * E_;                 // 3*768*768
    unsigned short* qkb = wtp + (size_t)3 * E_ * E_;              // 2*8192*768 (Q,K)
    unsigned short* vtg = qkb + (size_t)2 * 8192 * E_;            // 2*12*64*4096 (V^T)

    hipLaunchKernelGGL(cvt_x, dim3(2048), dim3(256), 0, stream, hs, xb, 8192 * E_ / 4);
    hipLaunchKernelGGL(cvt_w, dim3(24, 24, 3), dim3(32, 8), 0, stream, Wq, Wk, Wv, wtp);
    hipLaunchKernelGGL(qkv_gemm, dim3(64, 36), dim3(256), 0, stream, xb, wtp, bq, bk, bv, qkb, vtg);
    hipLaunchKernelGGL(attn, dim3(1536), dim3(256), 0, stream, qkb, vtg, am, out);
}

// Round 5
// 161.076 us; speedup vs baseline: 1.6919x; 1.6046x over previous
//
#include <hip/hip_runtime.h>
#include <hip/hip_bf16.h>
#include <cstdint>

#define B_ 2
#define S_ 4096
#define E_ 768
#define H_ 12
#define D_ 64

typedef __bf16 bf16x8 __attribute__((ext_vector_type(8)));
typedef __bf16 bf16x4 __attribute__((ext_vector_type(4)));
typedef float f32x4 __attribute__((ext_vector_type(4)));
typedef unsigned short ushort8 __attribute__((ext_vector_type(8)));
typedef unsigned short ushort4v __attribute__((ext_vector_type(4)));

static __device__ __forceinline__ unsigned short f2bf(float f) {
    union { float f; uint32_t u; } v; v.f = f;
    uint32_t u = v.u;
    u += 0x7FFFu + ((u >> 16) & 1u);
    return (unsigned short)(u >> 16);
}

static __device__ __forceinline__ void gl_lds16(const unsigned short* g, unsigned short* l) {
    __builtin_amdgcn_global_load_lds((const __attribute__((address_space(1))) unsigned int*)g,
                                     (__attribute__((address_space(3))) unsigned int*)l, 16, 0, 0);
}

// ---------------- convert hidden_states fp32 -> bf16 ----------------
__global__ void cvt_x(const float* __restrict__ x, unsigned short* __restrict__ xb, int n4) {
    int i = blockIdx.x * blockDim.x + threadIdx.x;
    int stride = gridDim.x * blockDim.x;
    for (; i < n4; i += stride) {
        float4 f = ((const float4*)x)[i];
        ushort4v o;
        o.x = f2bf(f.x); o.y = f2bf(f.y); o.z = f2bf(f.z); o.w = f2bf(f.w);
        ((ushort4v*)xb)[i] = o;
    }
}

// ---------------- convert + transpose weights: WT[n][k] = W[k][n], bf16 ----------------
__global__ void cvt_w(const float* __restrict__ Wq, const float* __restrict__ Wk,
                      const float* __restrict__ Wv, unsigned short* __restrict__ wt) {
    __shared__ float tl[32][33];
    int wsel = blockIdx.z;
    const float* src = wsel == 0 ? Wq : (wsel == 1 ? Wk : Wv);
    int tx = threadIdx.x, ty = threadIdx.y;
    int n0 = blockIdx.x * 32, k0 = blockIdx.y * 32;
    for (int i = 0; i < 4; i++) {
        int k = k0 + ty + i * 8;
        tl[ty + i * 8][tx] = src[(size_t)k * E_ + n0 + tx];
    }
    __syncthreads();
    unsigned short* dst = wt + (size_t)wsel * E_ * E_;
    for (int i = 0; i < 4; i++) {
        int n = n0 + ty + i * 8;
        dst[(size_t)n * E_ + k0 + tx] = f2bf(tl[tx][ty + i * 8]);
    }
}

// ---------------- QKV GEMM: Q,K row-major bf16; V stored TRANSPOSED [b][h][d][s] ----------------
#define GM 128
#define GN 64
#define AST 56

__global__ __launch_bounds__(256) void qkv_gemm(const unsigned short* __restrict__ xb,
        const unsigned short* __restrict__ wt,
        const float* __restrict__ biasq, const float* __restrict__ biask,
        const float* __restrict__ biasv,
        unsigned short* __restrict__ qk, unsigned short* __restrict__ vtg) {
    __shared__ unsigned short alds[GM * AST];
    int m0 = blockIdx.x * GM;
    int nblk = blockIdx.y * GN;          // 0..2304
    int wsel = nblk / E_;
    int nn0 = nblk % E_;
    const float* bias = wsel == 0 ? biasq : (wsel == 1 ? biask : biasv);
    float scale = wsel == 0 ? 0.125f : 1.0f;
    int t = threadIdx.x;
    int lane = t & 63, wv = t >> 6;
    int wm = wv >> 1, wn = wv & 1;
    int l15 = lane & 15, l4 = lane >> 4;

    f32x4 acc[4][2];
    for (int f = 0; f < 4; f++)
        for (int nf = 0; nf < 2; nf++)
            acc[f][nf] = (f32x4){0.f, 0.f, 0.f, 0.f};

    int srow = t >> 1;
    int scol = (t & 1) * 16;
    const unsigned short* xrow = xb + (size_t)(m0 + srow) * E_ + scol;
    unsigned short* sdst = alds + srow * AST + scol;
    const unsigned short* wbase = wt + (size_t)wsel * E_ * E_;

    for (int kk = 0; kk < E_; kk += 32) {
        ushort8 a0 = *(const ushort8*)(xrow + kk);
        ushort8 a1 = *(const ushort8*)(xrow + kk + 8);
        *(ushort8*)(sdst) = a0;
        *(ushort8*)(sdst + 8) = a1;
        __syncthreads();
        bf16x8 bfr[2];
        for (int nf = 0; nf < 2; nf++) {
            int nn = nn0 + wn * 32 + nf * 16 + l15;
            bfr[nf] = *(const bf16x8*)(wbase + (size_t)nn * E_ + kk + l4 * 8);
        }
        for (int f = 0; f < 4; f++) {
            bf16x8 afr = *(const bf16x8*)(alds + (wm * 64 + f * 16 + l15) * AST + l4 * 8);
            acc[f][0] = __builtin_amdgcn_mfma_f32_16x16x32_bf16(afr, bfr[0], acc[f][0], 0, 0, 0);
            acc[f][1] = __builtin_amdgcn_mfma_f32_16x16x32_bf16(afr, bfr[1], acc[f][1], 0, 0, 0);
        }
        __syncthreads();
    }
    for (int f = 0; f < 4; f++) {
        int row0 = m0 + wm * 64 + f * 16;
        for (int nf = 0; nf < 2; nf++) {
            int nn = nn0 + wn * 32 + nf * 16 + l15;
            float bb = bias[nn];
            for (int r = 0; r < 4; r++) {
                int row = row0 + l4 * 4 + r;
                float v = (acc[f][nf][r] + bb) * scale;
                unsigned short bv = f2bf(v);
                if (wsel < 2) {
                    qk[(size_t)wsel * 8192 * E_ + (size_t)row * E_ + nn] = bv;
                } else {
                    int b = row >> 12, s = row & 4095;
                    int hh = nn >> 6, dd = nn & 63;
                    vtg[((size_t)(b * H_ + hh) * D_ + dd) * S_ + s] = bv;
                }
            }
        }
    }
}

// ---------------- banded flash attention: LDS-staged K + V^T, swapped QK^T, O^T PV ----------------
__global__ __launch_bounds__(256) void attn(const unsigned short* __restrict__ qk,
        const unsigned short* __restrict__ vtg,
        const float* __restrict__ amask, float* __restrict__ out) {
    __shared__ unsigned short klds[2][2048];   // [buf] 32 rows x 64 cols, chunk-swizzled
    __shared__ unsigned short vlds[2][2048];   // [buf] V^T: 64 d-rows x 32 keys, linear
    __shared__ unsigned short plds[4][16 * 40];// per-wave P [16 q][32 keys], pad to 40

    // XCD-pinning: all 64 q-tiles of one (b,h) on one XCD
    int bid = blockIdx.x;
    int xcd = bid & 7;
    int j = bid >> 3;
    int qt = j & 63;
    int p_ = xcd + 8 * (j >> 6);
    int h = p_ % H_;
    int b = p_ / H_;

    int t = threadIdx.x, lane = t & 63, wv = t >> 6;
    int l15 = lane & 15, l4 = lane >> 4;
    const unsigned short* qp = qk;
    const unsigned short* kp = qk + (size_t)8192 * E_;
    size_t rowbase = (size_t)b * S_;
    int hcol = h * D_;
    const unsigned short* vth = vtg + (size_t)(b * H_ + h) * D_ * S_;
    const float* amb = amask + (size_t)b * S_;

    int q0 = qt * 64 + wv * 16;
    int myq = q0 + l15;
    bf16x8 qf[2];
    {
        const unsigned short* qrow = qp + (rowbase + myq) * E_ + hcol;
        qf[0] = *(const bf16x8*)(qrow + l4 * 8);
        qf[1] = *(const bf16x8*)(qrow + 32 + l4 * 8);
    }

    int kt0 = qt * 64 - 256;
    bool interior = (qt >= 4) && (qt <= 59);

    // staging thread-constant decode
    int rK = t >> 3;                                   // K row 0..31
    int cK = (((t & 7) ^ (rK & 7)) << 3);              // swizzled chunk -> elem off
    const unsigned short* kbase_g = kp + rowbase * E_ + hcol + cK;
    int dV = t >> 2;                                   // V^T d-row 0..63
    int kcV = (t & 3) << 3;                            // key chunk 0,8,16,24
    const unsigned short* vbase_g = vth + (size_t)dV * S_;

    auto stage = [&](int bt, int buf) {
        int kg = kt0 + bt * 32;
        int kk = min(max(kg + rK, 0), S_ - 1);
        gl_lds16(kbase_g + (size_t)kk * E_, &klds[buf][wv * 512]);
        int vb = min(max(kg + kcV, 0), S_ - 8);        // kg multiple of 32 -> chunk all-in or all-out
        gl_lds16(vbase_g + vb, &vlds[buf][wv * 512]);
    };

    float mrun = -1e8f, lpart = 0.f;
    f32x4 oaccT[4];
    #pragma unroll
    for (int d4 = 0; d4 < 4; d4++) oaccT[d4] = (f32x4){0.f, 0.f, 0.f, 0.f};
    unsigned short* pl = (unsigned short*)plds[wv];

    stage(0, 0);

    #pragma unroll 1
    for (int bt = 0; bt < 18; ++bt) {
        int buf = bt & 1;
        __syncthreads();                       // stage(bt) landed; buf^1 free
        if (bt + 1 < 18) stage(bt + 1, buf ^ 1);
        int kg = kt0 + bt * 32;

        // --- additive mask (key-only); issue loads early
        float fm[8];
        #pragma unroll
        for (int nt = 0; nt < 2; nt++) {
            int idx = kg + nt * 16 + l4 * 4;
            float4 a4 = make_float4(0.f, 0.f, 0.f, 0.f);
            if (idx >= 0 && idx <= S_ - 4) a4 = *(const float4*)(amb + idx);
            fm[nt * 4 + 0] = (a4.x != 0.f) ? -10000.f : 0.f;
            fm[nt * 4 + 1] = (a4.y != 0.f) ? -10000.f : 0.f;
            fm[nt * 4 + 2] = (a4.z != 0.f) ? -10000.f : 0.f;
            fm[nt * 4 + 3] = (a4.w != 0.f) ? -10000.f : 0.f;
        }

        // --- K A-frags from swizzled LDS
        const unsigned short* kb = &klds[buf][l15 * 64];
        int c0 = ((l4 ^ (l15 & 7)) << 3);
        int c1 = (((4 + l4) ^ (l15 & 7)) << 3);
        bf16x8 kf00 = *(const bf16x8*)(kb + c0);
        bf16x8 kf01 = *(const bf16x8*)(kb + c1);
        bf16x8 kf10 = *(const bf16x8*)(kb + 1024 + c0);
        bf16x8 kf11 = *(const bf16x8*)(kb + 1024 + c1);

        // --- V^T A-frags (plain b128): vf[d4] = V^T[d4*16+l15][keys l4*8..+7]
        bf16x8 vf[4];
        #pragma unroll
        for (int d4 = 0; d4 < 4; d4++)
            vf[d4] = *(const bf16x8*)(&vlds[buf][(d4 * 16 + l15) * 32 + l4 * 8]);

        // --- swapped QK^T: st[nt][r] = S^T[key=kg+nt*16+l4*4+r][q=myq]
        f32x4 z = (f32x4){0.f, 0.f, 0.f, 0.f};
        f32x4 st0 = __builtin_amdgcn_mfma_f32_16x16x32_bf16(kf00, qf[0], z, 0, 0, 0);
        st0 = __builtin_amdgcn_mfma_f32_16x16x32_bf16(kf01, qf[1], st0, 0, 0, 0);
        f32x4 st1 = __builtin_amdgcn_mfma_f32_16x16x32_bf16(kf10, qf[0], z, 0, 0, 0);
        st1 = __builtin_amdgcn_mfma_f32_16x16x32_bf16(kf11, qf[1], st1, 0, 0, 0);

        bool full = interior && (bt >= 1 + (wv >> 1)) && (bt <= 15 + (wv >> 1));
        float sv[8];
        if (full) {
            #pragma unroll
            for (int r = 0; r < 4; r++) { sv[r] = st0[r] + fm[r]; sv[4 + r] = st1[r] + fm[4 + r]; }
        } else {
            #pragma unroll
            for (int i = 0; i < 8; i++) {
                int key = kg + (i >> 2) * 16 + l4 * 4 + (i & 3);
                int dd = key - myq;
                bool valid = (key >= 0) && (key < S_) && (dd <= 256) && (dd >= -256);
                float s = (i < 4) ? st0[i & 3] : st1[i & 3];
                sv[i] = valid ? (s + fm[i]) : -1e30f;
            }
        }

        // --- defer-max online softmax
        float mt = sv[0];
        #pragma unroll
        for (int i = 1; i < 8; i++) mt = fmaxf(mt, sv[i]);
        if (__any(mt - mrun > 8.f)) {
            float mw = fmaxf(mt, __shfl_xor(mt, 16));
            mw = fmaxf(mw, __shfl_xor(mw, 32));
            float mnew = fmaxf(mrun, mw);
            float sc = __expf(mrun - mnew);   // uniform over l4 for fixed l15=q
            mrun = mnew;
            lpart *= sc;
            #pragma unroll
            for (int d4 = 0; d4 < 4; d4++) {
                oaccT[d4][0] *= sc; oaccT[d4][1] *= sc; oaccT[d4][2] *= sc; oaccT[d4][3] *= sc;
            }
        }
        bf16x4 pb0, pb1;
        float ps = 0.f;
        #pragma unroll
        for (int r = 0; r < 4; r++) {
            float e0 = __expf(sv[r] - mrun);
            float e1 = __expf(sv[4 + r] - mrun);
            ps += e0 + e1;
            pb0[r] = (__bf16)e0;
            pb1[r] = (__bf16)e1;
        }
        lpart += ps;

        // --- P round-trip through per-wave LDS: P[q=l15][key]
        *(ushort4v*)(pl + l15 * 40 + l4 * 4)      = __builtin_bit_cast(ushort4v, pb0);
        *(ushort4v*)(pl + l15 * 40 + 16 + l4 * 4) = __builtin_bit_cast(ushort4v, pb1);
        asm volatile("s_waitcnt lgkmcnt(0)" ::: "memory");
        __builtin_amdgcn_sched_barrier(0);
        bf16x8 pf = *(const bf16x8*)(pl + l15 * 40 + l4 * 8);   // P^T B-frag

        // --- PV: O^T[d][q] += V^T x P^T
        #pragma unroll
        for (int d4 = 0; d4 < 4; d4++)
            oaccT[d4] = __builtin_amdgcn_mfma_f32_16x16x32_bf16(vf[d4], pf, oaccT[d4], 0, 0, 0);
    }

    // --- epilogue (all lane-local: q = l15)
    float lsum = lpart + __shfl_xor(lpart, 16);
    lsum += __shfl_xor(lsum, 32);
    float inv = 1.0f / lsum;
    if (amb[q0 + l15] < 0.f) inv = 0.f;
    float* orow = out + (rowbase + q0 + l15) * E_ + hcol;
    #pragma unroll
    for (int d4 = 0; d4 < 4; d4++) {
        float4 o4;
        o4.x = oaccT[d4][0] * inv;
        o4.y = oaccT[d4][1] * inv;
        o4.z = oaccT[d4][2] * inv;
        o4.w = oaccT[d4][3] * inv;
        *(float4*)(orow + d4 * 16 + l4 * 4) = o4;
    }
}

extern "C" void kernel_launch(void* const* d_in, const int* in_sizes, int n_in,
                              void* d_out, int out_size, void* d_ws, size_t ws_size,
                              hipStream_t stream) {
    const float* hs = (const float*)d_in[0];
    const float* am = (const float*)d_in[1];
    const float* Wq = (const float*)d_in[2];
    const float* bq = (const float*)d_in[3];
    const float* Wk = (const float*)d_in[4];
    const float* bk = (const float*)d_in[5];
    const float* Wv = (const float*)d_in[6];
    const float* bv = (const float*)d_in[7];
    float* out = (float*)d_out;
    unsigned short* xb  = (unsigned short*)d_ws;                  // 8192*768
    unsigned short* wtp = xb + (size_t)8192 * E_;                 // 3*768*768
    unsigned short* qkb = wtp + (size_t)3 * E_ * E_;              // 2*8192*768 (Q,K)
    unsigned short* vtg = qkb + (size_t)2 * 8192 * E_;            // 2*12*64*4096 (V^T)

    hipLaunchKernelGGL(cvt_x, dim3(2048), dim3(256), 0, stream, hs, xb, 8192 * E_ / 4);
    hipLaunchKernelGGL(cvt_w, dim3(24, 24, 3), dim3(32, 8), 0, stream, Wq, Wk, Wv, wtp);
    hipLaunchKernelGGL(qkv_gemm, dim3(64, 36), dim3(256), 0, stream, xb, wtp, bq, bk, bv, qkb, vtg);
    hipLaunchKernelGGL(attn, dim3(1536), dim3(256), 0, stream, qkb, vtg, am, out);
}

// Round 6
// 137.979 us; speedup vs baseline: 1.9751x; 1.1674x over previous
//
#include <hip/hip_runtime.h>
#include <hip/hip_bf16.h>
#include <cstdint>

#define B_ 2
#define S_ 4096
#define E_ 768
#define H_ 12
#define D_ 64

typedef __bf16 bf16x8 __attribute__((ext_vector_type(8)));
typedef __bf16 bf16x4 __attribute__((ext_vector_type(4)));
typedef float f32x4 __attribute__((ext_vector_type(4)));
typedef unsigned short ushort8 __attribute__((ext_vector_type(8)));
typedef unsigned short ushort4v __attribute__((ext_vector_type(4)));

static __device__ __forceinline__ unsigned short f2bf(float f) {
    union { float f; uint32_t u; } v; v.f = f;
    uint32_t u = v.u;
    u += 0x7FFFu + ((u >> 16) & 1u);
    return (unsigned short)(u >> 16);
}

static __device__ __forceinline__ void gl_lds16(const unsigned short* g, unsigned short* l) {
    __builtin_amdgcn_global_load_lds((const __attribute__((address_space(1))) unsigned int*)g,
                                     (__attribute__((address_space(3))) unsigned int*)l, 16, 0, 0);
}

// ---------------- convert hidden_states fp32 -> bf16 ----------------
__global__ void cvt_x(const float* __restrict__ x, unsigned short* __restrict__ xb, int n4) {
    int i = blockIdx.x * blockDim.x + threadIdx.x;
    int stride = gridDim.x * blockDim.x;
    for (; i < n4; i += stride) {
        float4 f = ((const float4*)x)[i];
        ushort4v o;
        o.x = f2bf(f.x); o.y = f2bf(f.y); o.z = f2bf(f.z); o.w = f2bf(f.w);
        ((ushort4v*)xb)[i] = o;
    }
}

// ---------------- convert + transpose weights: WT[n][k] = W[k][n], bf16 ----------------
__global__ void cvt_w(const float* __restrict__ Wq, const float* __restrict__ Wk,
                      const float* __restrict__ Wv, unsigned short* __restrict__ wt) {
    __shared__ float tl[32][33];
    int wsel = blockIdx.z;
    const float* src = wsel == 0 ? Wq : (wsel == 1 ? Wk : Wv);
    int tx = threadIdx.x, ty = threadIdx.y;
    int n0 = blockIdx.x * 32, k0 = blockIdx.y * 32;
    for (int i = 0; i < 4; i++) {
        int k = k0 + ty + i * 8;
        tl[ty + i * 8][tx] = src[(size_t)k * E_ + n0 + tx];
    }
    __syncthreads();
    unsigned short* dst = wt + (size_t)wsel * E_ * E_;
    for (int i = 0; i < 4; i++) {
        int n = n0 + ty + i * 8;
        dst[(size_t)n * E_ + k0 + tx] = f2bf(tl[tx][ty + i * 8]);
    }
}

// ---------------- QKV GEMM: 128x128x32 2-phase double-buffered, gl_lds staging ----------------
// Q,K row-major bf16; V stored TRANSPOSED [b][h][d][s]
__global__ __launch_bounds__(256) void qkv_gemm(const unsigned short* __restrict__ xb,
        const unsigned short* __restrict__ wt,
        const float* __restrict__ biasq, const float* __restrict__ biask,
        const float* __restrict__ biasv,
        unsigned short* __restrict__ qk, unsigned short* __restrict__ vtg) {
    __shared__ unsigned short ldsA[2][4096];   // [buf] 128 rows x 32 k, chunk-swizzled
    __shared__ unsigned short ldsB[2][4096];

    // XCD-chunked decode: each XCD owns 144 consecutive wgids -> 2-3 B-panels L2-resident
    int bid = blockIdx.x;
    int wg = (bid & 7) * 144 + (bid >> 3);
    int mtile = wg & 63, ntile = wg >> 6;      // 64 x 18
    int m0 = mtile * 128;
    int wsel = ntile / 6;
    int nb0 = ntile * 128 - wsel * E_;         // col offset within this weight
    const float* bias = wsel == 0 ? biasq : (wsel == 1 ? biask : biasv);
    float scale = wsel == 0 ? 0.125f : 1.0f;

    int t = threadIdx.x, lane = t & 63, w = t >> 6;
    int l15 = lane & 15, l4 = lane >> 4;
    int wm = w >> 1, wn = w & 1;

    // staging decode: lane covers row rs (within 64-half), slot = lane&3;
    // global chunk = slot ^ ((row>>1)&3)  (same for both halves since 64 = 0 mod 8)
    int rs = w * 16 + (lane >> 2);
    int cg = ((lane & 3) ^ ((rs >> 1) & 3)) * 8;
    const unsigned short* agp = xb + (size_t)(m0 + rs) * E_ + cg;
    const unsigned short* bgp = wt + (size_t)(wsel * E_ + nb0 + rs) * E_ + cg;

    f32x4 acc[4][4];
    #pragma unroll
    for (int f = 0; f < 4; f++)
        #pragma unroll
        for (int g = 0; g < 4; g++)
            acc[f][g] = (f32x4){0.f, 0.f, 0.f, 0.f};

    auto stage = [&](int kk, int buf) {
        gl_lds16(agp + kk,             &ldsA[buf][w * 512]);
        gl_lds16(agp + kk + 64 * E_,   &ldsA[buf][2048 + w * 512]);
        gl_lds16(bgp + kk,             &ldsB[buf][w * 512]);
        gl_lds16(bgp + kk + 64 * E_,   &ldsB[buf][2048 + w * 512]);
    };

    stage(0, 0);
    __syncthreads();

    int sA = (l4 ^ ((l15 >> 1) & 3)) * 8;      // swizzled k-slot for frag reads

    #pragma unroll 1
    for (int kt = 0; kt < 24; ++kt) {
        int buf = kt & 1;
        if (kt < 23) stage((kt + 1) * 32, buf ^ 1);
        bf16x8 a[4], b[4];
        #pragma unroll
        for (int f = 0; f < 4; f++)
            a[f] = *(const bf16x8*)&ldsA[buf][(wm * 64 + f * 16 + l15) * 32 + sA];
        #pragma unroll
        for (int g = 0; g < 4; g++)
            b[g] = *(const bf16x8*)&ldsB[buf][(wn * 64 + g * 16 + l15) * 32 + sA];
        #pragma unroll
        for (int f = 0; f < 4; f++)
            #pragma unroll
            for (int g = 0; g < 4; g++)
                acc[f][g] = __builtin_amdgcn_mfma_f32_16x16x32_bf16(a[f], b[g], acc[f][g], 0, 0, 0);
        __syncthreads();   // drains vmcnt (stage done) + all reads of buf done
    }

    // epilogue
    #pragma unroll
    for (int f = 0; f < 4; f++) {
        int row0 = m0 + wm * 64 + f * 16 + l4 * 4;
        #pragma unroll
        for (int g = 0; g < 4; g++) {
            int col = nb0 + wn * 64 + g * 16 + l15;
            float bb = bias[col];
            #pragma unroll
            for (int r = 0; r < 4; r++) {
                int row = row0 + r;
                float v = (acc[f][g][r] + bb) * scale;
                unsigned short bv = f2bf(v);
                if (wsel < 2) {
                    qk[(size_t)wsel * 8192 * E_ + (size_t)row * E_ + col] = bv;
                } else {
                    int b2 = row >> 12, s = row & 4095;
                    int hh = col >> 6, dd = col & 63;
                    vtg[((size_t)(b2 * H_ + hh) * D_ + dd) * S_ + s] = bv;
                }
            }
        }
    }
}

// ---------------- banded flash attention: LDS-staged K + V^T, swapped QK^T, O^T PV ----------------
__global__ __launch_bounds__(256) void attn(const unsigned short* __restrict__ qk,
        const unsigned short* __restrict__ vtg,
        const float* __restrict__ amask, float* __restrict__ out) {
    __shared__ unsigned short klds[2][2048];   // [buf] 32 rows x 64 cols, chunk-swizzled
    __shared__ unsigned short vlds[2][2048];   // [buf] V^T: 64 d-rows x 32 keys, linear
    __shared__ unsigned short plds[4][16 * 40];// per-wave P [16 q][32 keys], pad to 40

    // XCD-pinning: all 64 q-tiles of one (b,h) on one XCD
    int bid = blockIdx.x;
    int xcd = bid & 7;
    int j = bid >> 3;
    int qt = j & 63;
    int p_ = xcd + 8 * (j >> 6);
    int h = p_ % H_;
    int b = p_ / H_;

    int t = threadIdx.x, lane = t & 63, wv = t >> 6;
    int l15 = lane & 15, l4 = lane >> 4;
    const unsigned short* qp = qk;
    const unsigned short* kp = qk + (size_t)8192 * E_;
    size_t rowbase = (size_t)b * S_;
    int hcol = h * D_;
    const unsigned short* vth = vtg + (size_t)(b * H_ + h) * D_ * S_;
    const float* amb = amask + (size_t)b * S_;

    int q0 = qt * 64 + wv * 16;
    int myq = q0 + l15;
    bf16x8 qf[2];
    {
        const unsigned short* qrow = qp + (rowbase + myq) * E_ + hcol;
        qf[0] = *(const bf16x8*)(qrow + l4 * 8);
        qf[1] = *(const bf16x8*)(qrow + 32 + l4 * 8);
    }

    int kt0 = qt * 64 - 256;
    bool interior = (qt >= 4) && (qt <= 59);

    // staging thread-constant decode
    int rK = t >> 3;                                   // K row 0..31
    int cK = (((t & 7) ^ (rK & 7)) << 3);              // swizzled chunk -> elem off
    const unsigned short* kbase_g = kp + rowbase * E_ + hcol + cK;
    int dV = t >> 2;                                   // V^T d-row 0..63
    int kcV = (t & 3) << 3;                            // key chunk 0,8,16,24
    const unsigned short* vbase_g = vth + (size_t)dV * S_;

    auto stage = [&](int bt, int buf) {
        int kg = kt0 + bt * 32;
        int kk = min(max(kg + rK, 0), S_ - 1);
        gl_lds16(kbase_g + (size_t)kk * E_, &klds[buf][wv * 512]);
        int vb = min(max(kg + kcV, 0), S_ - 8);        // kg multiple of 32 -> chunk all-in or all-out
        gl_lds16(vbase_g + vb, &vlds[buf][wv * 512]);
    };

    float mrun = -1e8f, lpart = 0.f;
    f32x4 oaccT[4];
    #pragma unroll
    for (int d4 = 0; d4 < 4; d4++) oaccT[d4] = (f32x4){0.f, 0.f, 0.f, 0.f};
    unsigned short* pl = (unsigned short*)plds[wv];

    stage(0, 0);

    #pragma unroll 1
    for (int bt = 0; bt < 18; ++bt) {
        int buf = bt & 1;
        __syncthreads();                       // stage(bt) landed; buf^1 free
        if (bt + 1 < 18) stage(bt + 1, buf ^ 1);
        int kg = kt0 + bt * 32;

        // --- additive mask (key-only); issue loads early
        float fm[8];
        #pragma unroll
        for (int nt = 0; nt < 2; nt++) {
            int idx = kg + nt * 16 + l4 * 4;
            float4 a4 = make_float4(0.f, 0.f, 0.f, 0.f);
            if (idx >= 0 && idx <= S_ - 4) a4 = *(const float4*)(amb + idx);
            fm[nt * 4 + 0] = (a4.x != 0.f) ? -10000.f : 0.f;
            fm[nt * 4 + 1] = (a4.y != 0.f) ? -10000.f : 0.f;
            fm[nt * 4 + 2] = (a4.z != 0.f) ? -10000.f : 0.f;
            fm[nt * 4 + 3] = (a4.w != 0.f) ? -10000.f : 0.f;
        }

        // --- K A-frags from swizzled LDS
        const unsigned short* kb = &klds[buf][l15 * 64];
        int c0 = ((l4 ^ (l15 & 7)) << 3);
        int c1 = (((4 + l4) ^ (l15 & 7)) << 3);
        bf16x8 kf00 = *(const bf16x8*)(kb + c0);
        bf16x8 kf01 = *(const bf16x8*)(kb + c1);
        bf16x8 kf10 = *(const bf16x8*)(kb + 1024 + c0);
        bf16x8 kf11 = *(const bf16x8*)(kb + 1024 + c1);

        // --- V^T A-frags (plain b128): vf[d4] = V^T[d4*16+l15][keys l4*8..+7]
        bf16x8 vf[4];
        #pragma unroll
        for (int d4 = 0; d4 < 4; d4++)
            vf[d4] = *(const bf16x8*)(&vlds[buf][(d4 * 16 + l15) * 32 + l4 * 8]);

        // --- swapped QK^T: st[nt][r] = S^T[key=kg+nt*16+l4*4+r][q=myq]
        f32x4 z = (f32x4){0.f, 0.f, 0.f, 0.f};
        f32x4 st0 = __builtin_amdgcn_mfma_f32_16x16x32_bf16(kf00, qf[0], z, 0, 0, 0);
        st0 = __builtin_amdgcn_mfma_f32_16x16x32_bf16(kf01, qf[1], st0, 0, 0, 0);
        f32x4 st1 = __builtin_amdgcn_mfma_f32_16x16x32_bf16(kf10, qf[0], z, 0, 0, 0);
        st1 = __builtin_amdgcn_mfma_f32_16x16x32_bf16(kf11, qf[1], st1, 0, 0, 0);

        bool full = interior && (bt >= 1 + (wv >> 1)) && (bt <= 15 + (wv >> 1));
        float sv[8];
        if (full) {
            #pragma unroll
            for (int r = 0; r < 4; r++) { sv[r] = st0[r] + fm[r]; sv[4 + r] = st1[r] + fm[4 + r]; }
        } else {
            #pragma unroll
            for (int i = 0; i < 8; i++) {
                int key = kg + (i >> 2) * 16 + l4 * 4 + (i & 3);
                int dd = key - myq;
                bool valid = (key >= 0) && (key < S_) && (dd <= 256) && (dd >= -256);
                float s = (i < 4) ? st0[i & 3] : st1[i & 3];
                sv[i] = valid ? (s + fm[i]) : -1e30f;
            }
        }

        // --- defer-max online softmax
        float mt = sv[0];
        #pragma unroll
        for (int i = 1; i < 8; i++) mt = fmaxf(mt, sv[i]);
        if (__any(mt - mrun > 8.f)) {
            float mw = fmaxf(mt, __shfl_xor(mt, 16));
            mw = fmaxf(mw, __shfl_xor(mw, 32));
            float mnew = fmaxf(mrun, mw);
            float sc = __expf(mrun - mnew);   // uniform over l4 for fixed l15=q
            mrun = mnew;
            lpart *= sc;
            #pragma unroll
            for (int d4 = 0; d4 < 4; d4++) {
                oaccT[d4][0] *= sc; oaccT[d4][1] *= sc; oaccT[d4][2] *= sc; oaccT[d4][3] *= sc;
            }
        }
        bf16x4 pb0, pb1;
        float ps = 0.f;
        #pragma unroll
        for (int r = 0; r < 4; r++) {
            float e0 = __expf(sv[r] - mrun);
            float e1 = __expf(sv[4 + r] - mrun);
            ps += e0 + e1;
            pb0[r] = (__bf16)e0;
            pb1[r] = (__bf16)e1;
        }
        lpart += ps;

        // --- P round-trip through per-wave LDS: P[q=l15][key]
        *(ushort4v*)(pl + l15 * 40 + l4 * 4)      = __builtin_bit_cast(ushort4v, pb0);
        *(ushort4v*)(pl + l15 * 40 + 16 + l4 * 4) = __builtin_bit_cast(ushort4v, pb1);
        asm volatile("s_waitcnt lgkmcnt(0)" ::: "memory");
        __builtin_amdgcn_sched_barrier(0);
        bf16x8 pf = *(const bf16x8*)(pl + l15 * 40 + l4 * 8);   // P^T B-frag

        // --- PV: O^T[d][q] += V^T x P^T
        #pragma unroll
        for (int d4 = 0; d4 < 4; d4++)
            oaccT[d4] = __builtin_amdgcn_mfma_f32_16x16x32_bf16(vf[d4], pf, oaccT[d4], 0, 0, 0);
    }

    // --- epilogue (all lane-local: q = l15)
    float lsum = lpart + __shfl_xor(lpart, 16);
    lsum += __shfl_xor(lsum, 32);
    float inv = 1.0f / lsum;
    if (amb[q0 + l15] < 0.f) inv = 0.f;
    float* orow = out + (rowbase + q0 + l15) * E_ + hcol;
    #pragma unroll
    for (int d4 = 0; d4 < 4; d4++) {
        float4 o4;
        o4.x = oaccT[d4][0] * inv;
        o4.y = oaccT[d4][1] * inv;
        o4.z = oaccT[d4][2] * inv;
        o4.w = oaccT[d4][3] * inv;
        *(float4*)(orow + d4 * 16 + l4 * 4) = o4;
    }
}

extern "C" void kernel_launch(void* const* d_in, const int* in_sizes, int n_in,
                              void* d_out, int out_size, void* d_ws, size_t ws_size,
                              hipStream_t stream) {
    const float* hs = (const float*)d_in[0];
    const float* am = (const float*)d_in[1];
    const float* Wq = (const float*)d_in[2];
    const float* bq = (const float*)d_in[3];
    const float* Wk = (const float*)d_in[4];
    const float* bk = (const float*)d_in[5];
    const float* Wv = (const float*)d_in[6];
    const float* bv = (const float*)d_in[7];
    float* out = (float*)d_out;
    unsigned short* xb  = (unsigned short*)d_ws;                  // 8192*768
    unsigned short* wtp = xb + (size_t)8192 * E_;                 // 3*768*768
    unsigned short* qkb = wtp + (size_t)3 * E_ * E_;              // 2*8192*768 (Q,K)
    unsigned short* vtg = qkb + (size_t)2 * 8192 * E_;            // 2*12*64*4096 (V^T)

    hipLaunchKernelGGL(cvt_x, dim3(2048), dim3(256), 0, stream, hs, xb, 8192 * E_ / 4);
    hipLaunchKernelGGL(cvt_w, dim3(24, 24, 3), dim3(32, 8), 0, stream, Wq, Wk, Wv, wtp);
    hipLaunchKernelGGL(qkv_gemm, dim3(1152), dim3(256), 0, stream, xb, wtp, bq, bk, bv, qkb, vtg);
    hipLaunchKernelGGL(attn, dim3(1536), dim3(256), 0, stream, qkb, vtg, am, out);
}